// Round 6
// baseline (301.332 us; speedup 1.0000x reference)
//
#include <hip/hip_runtime.h>
#include <math.h>

#define NQ 131072
#define MN 8192
#define NINT 1024          // internal nodes: 8*i+1 < 8192 -> i <= 1023
#define DEPTHT 16
#define EPSD 1e-6f
#define BIGD 1e9f

// ---------------------------------------------------------------------------
// R15. Journal (do not retry):
//  R10 convoy barriers: 77.9us (phase-lock kills wave-drift hiding).
//  R11 w3->LDS hybrid: 80.0us (DS+SMEM share lgkmcnt; full drains kill
//    prefetch). Never mix DS into the weight loop.
//  R12 traverse bank decorrelation: neutral.
//  R13 half-grid split: mlp wall is grid-independent -> PER-WAVE LATENCY
//    bound; memory system idle.
//  R14 VMEM+readlane: 114us. readlane doubles VALU issue and every
//    v_readlane->SGPR->v_fma pair eats a VALU-writes-SGPR hazard. Dead end.
//  KEY R14 insight: VGPR_Count=68 proves h1[100] was never VGPR-resident;
//    SGPR starvation (102-file vs 100-float rows) forces chunked s_load
//    bursts with lgkmcnt(0) full drains — that is the 1650 cyc/row.
//  R15 fix: w2/w3/b2 via UNIFORM-ADDRESS VMEM into VGPRs (one L1
//    transaction broadcast, in-order vmcnt -> partial waits, 4-deep chunk
//    pipeline). No readlane, no SMEM, SGPRs freed, h1 stays in VGPRs.
//    dz=0 laundered through inline-asm defeats uniform-load scalarization.
// FP dag bit-identical everywhere (R5 contract).
// ---------------------------------------------------------------------------

// ---------------------------------------------------------------------------
// Kernel 0: W2 [k][j] -> W2T [j][k] (rows 100 floats, 400B, 16B-aligned);
//           W3 [j][k] -> W3P [j][32] (padded rows for aligned dwordx4).
// ---------------------------------------------------------------------------
__global__ __launch_bounds__(256) void transpose_w2(
    const float* __restrict__ W2, float* __restrict__ W2T,
    const float* __restrict__ W3, float* __restrict__ W3P)
{
    const int i = blockIdx.x * 256 + threadIdx.x;
    if (i < 100 * 100) {
        const int k = i / 100, j = i - k * 100;
        W2T[j * 100 + k] = W2[i];
    } else if (i < 100 * 100 + 100 * 32) {
        const int t = i - 100 * 100;
        const int jj = t >> 5, kk = t & 31;
        W3P[t] = (kk < 30) ? W3[jj * 30 + kk] : 0.0f;
    }
}

// ---------------------------------------------------------------------------
// Kernel 1: MLP 2 -> 100 -> 100 -> 30 -> 2, one row per thread.
// ---------------------------------------------------------------------------
__global__ __launch_bounds__(64) void mlp_kernel(
    const float* __restrict__ x, const float* __restrict__ nd,
    const float* __restrict__ W1, const float* __restrict__ b1,
    const float* __restrict__ W2T, const float* __restrict__ b2,
    const float* __restrict__ W3P, const float* __restrict__ b3,
    const float* __restrict__ W4, const float* __restrict__ b4,
    float* __restrict__ outv)
{
    const int r = blockIdx.x * 64 + threadIdx.x;    // 2176*64 = 139264 exact
    const float2 xi = (r < NQ) ? ((const float2*)x)[r]
                               : ((const float2*)nd)[r - NQ];

    // divergence launderer: dz == 0, but lives in a VGPR the optimizer
    // cannot fold -> weight loads stay VMEM (global_load), never s_load.
    int dz = 0;
    asm volatile("" : "+v"(dz));

    // ---- layer 1: h1[100] in VGPRs (constant indices only) ----
    float h1[100];
#pragma unroll
    for (int k = 0; k < 100; ++k)
        h1[k] = fmaxf(fmaf(xi.x, W1[k], fmaf(xi.y, W1[100 + k], b1[k])), 0.0f);

    // ---- layers 2+3 fused; weights stream via uniform VMEM broadcast ----
    float h3[30];
#pragma unroll
    for (int jj = 0; jj < 30; ++jj) h3[jj] = b3[jj];

    const float4* w2v = (const float4*)W2T;   // 25 float4 per row
    const float4* w3v = (const float4*)W3P;   // 8 float4 per row (padded)

    for (int j = 0; j < 100; ++j) {
        const float4* wr = w2v + j * 25 + dz;
        const float4* vr = w3v + j * 8 + dz;

        float4 cb[4];                          // 4-deep w2 chunk pipeline
#pragma unroll
        for (int c = 0; c < 4; ++c) cb[c] = wr[c];
        float4 v[8];                           // w3 row, issued early:
#pragma unroll
        for (int c = 0; c < 8; ++c) v[c] = vr[c];   // full-row compute as cover
        const float bj = b2[j + dz];

        float a0 = 0.0f, a1 = 0.0f;            // 2 chains, exact R0 order
#pragma unroll
        for (int c = 0; c < 25; ++c) {
            const float4 w = cb[c & 3];        // static after unroll
            a0 = fmaf(h1[4 * c + 0], w.x, a0); // k = 4c   (even chain)
            a1 = fmaf(h1[4 * c + 1], w.y, a1); // k = 4c+1 (odd chain)
            a0 = fmaf(h1[4 * c + 2], w.z, a0); // k = 4c+2
            a1 = fmaf(h1[4 * c + 3], w.w, a1); // k = 4c+3
            if (c + 4 < 25) cb[c & 3] = wr[c + 4];   // refill slot
        }
        const float h2j = fmaxf(a0 + a1 + bj, 0.0f);
#pragma unroll
        for (int jj = 0; jj < 30; ++jj) {
            const float4 wv = v[jj >> 2];
            const float w3e = ((jj & 3) == 0) ? wv.x :
                              ((jj & 3) == 1) ? wv.y :
                              ((jj & 3) == 2) ? wv.z : wv.w;
            h3[jj] = fmaf(h2j, w3e, h3[jj]);
        }
    }

    // ---- layer 4: 30 -> 2 ----
    float o0 = b4[0], o1 = b4[1];
#pragma unroll
    for (int k = 0; k < 30; ++k) {
        const float h = fmaxf(h3[k], 0.0f);
        o0 = fmaf(h, W4[2 * k],     o0);
        o1 = fmaf(h, W4[2 * k + 1], o1);
    }
    ((float2*)outv)[r] = make_float2(o0, o1);
}

// ---------------------------------------------------------------------------
// Kernel 2: per-internal-node stop-branch class mixture (query-independent).
// Verbatim (passed every round).
// ---------------------------------------------------------------------------
__global__ __launch_bounds__(256) void prob2_kernel(
    const float2* __restrict__ emb, const float2* __restrict__ cls,
    float2* __restrict__ p2)
{
    const int i = blockIdx.x * 256 + threadIdx.x;   // 0..1023
    const float2 ei = emb[i];
    const int base = 8 * i + 1;

    float d2[8];
    float m2 = BIGD;
#pragma unroll
    for (int j = 0; j < 8; ++j) {
        const int c = base + j;
        const bool v = c < MN;
        const float2 ec = emb[v ? c : 0];
        const float dx = ei.x - ec.x + EPSD;
        const float dy = ei.y - ec.y + EPSD;
        d2[j] = v ? sqrtf(dx * dx + dy * dy) : BIGD;
        m2 = fminf(m2, d2[j]);
    }
    float s2 = 0.0f, mix0 = 0.0f, mix1 = 0.0f;
#pragma unroll
    for (int j = 0; j < 8; ++j) {
        const float w = expf(m2 - d2[j]);   // exactly 0 for pads
        s2 += w;
        const int c = base + j;
        if (c < MN) {
            const float2 cv = cls[c];
            mix0 = fmaf(w, cv.x, mix0);
            mix1 = fmaf(w, cv.y, mix1);
        }
    }
    mix0 /= s2;
    mix1 /= s2;
    p2[i] = make_float2(logf(fmaxf(mix0, 1e-30f)),
                        logf(fmaxf(mix1, 1e-30f)));
}

// ---------------------------------------------------------------------------
// Kernel 3: per-query traversal, single 512-block dispatch.
// R12 bank-decorrelated layout kept (neutral, not harmful).
// d0 carried across steps (child dist at t == d0 at t+1), verbatim.
// ---------------------------------------------------------------------------
#define SEMB_F (2 * MN + MN / 8)    // 17408 floats = 68 KB

__global__ __launch_bounds__(256) void traverse_kernel(
    const float* __restrict__ qx, const float2* __restrict__ emb,
    const float2* __restrict__ p2g, float* __restrict__ out)
{
    __shared__ float sembf[SEMB_F];  // 68 KB, padded layout
    __shared__ float2 sp2[NINT];     // 8 KB
    {
        for (int c = threadIdx.x; c < MN; c += 256) {   // coalesced 8B/lane
            const float2 e = emb[c];
            const int off = 2 * c + (c >> 3);
            sembf[off]     = e.x;
            sembf[off + 1] = e.y;
        }
        const float4* gp = (const float4*)p2g;
        float4* sp = (float4*)sp2;
#pragma unroll
        for (int t = 0; t < 2; ++t)
            sp[threadIdx.x + 256 * t] = gp[threadIdx.x + 256 * t];
    }
    __syncthreads();

    const int qi = blockIdx.x * 256 + threadIdx.x;  // grid = NQ/256
    const float2 qv = ((const float2*)qx)[qi];

    int cur = 0;
    float d0;
    {
        const float ex = sembf[0], ey = sembf[1];   // node 0 at offset 0
        const float dx = ex - qv.x + EPSD;
        const float dy = ey - qv.y + EPSD;
        d0 = sqrtf(dx * dx + dy * dy);
    }
    float prob = 0.0f, out0 = 0.0f, out1 = 0.0f;
    bool done = false;

    for (int t = 0; t < DEPTHT; ++t) {
        if (__all(done)) break;
        if (!done) {
            const int base = 8 * cur + 1;
            const int boff = 17 * cur + 2;          // float offset of child 0

            float dc[8];
#pragma unroll
            for (int j = 0; j < 8; ++j) {
                const int c = base + j;
                const bool v = c < MN;
                const int off = v ? (boff + 2 * j + (j == 7 ? 1 : 0)) : 0;
                const float ex = sembf[off];
                const float ey = sembf[off + 1];
                const float dx = ex - qv.x + EPSD;
                const float dy = ey - qv.y + EPSD;
                dc[j] = v ? sqrtf(dx * dx + dy * dy) : BIGD;
            }

            // argmax(log_softmax(-d)) == first argmin(d)
            float dmin = d0;
            int amax = 0;
#pragma unroll
            for (int j = 0; j < 8; ++j)
                if (dc[j] < dmin) { dmin = dc[j]; amax = j + 1; }

            float s = expf(dmin - d0);
#pragma unroll
            for (int j = 0; j < 8; ++j) s += expf(dmin - dc[j]);
            const float max_prob = -logf(s);
            // quirk: t==0 adds max_prob twice
            const float prob_new = prob + max_prob + ((t == 0) ? max_prob : 0.0f);

            if (amax == 0) {
                if (base < MN) {                  // internal node
                    const float2 pp = sp2[cur];
                    out0 = prob_new + pp.x;
                    out1 = prob_new + pp.y;
                } else {                          // leaf
                    out0 = prob_new;
                    out1 = prob_new;
                }
                done = true;
            } else {
                cur  = base + amax - 1;
                d0   = dmin;                      // child dist == next d0
                prob = prob_new;
            }
        }
    }

    ((float2*)out)[qi] = make_float2(out0, out1);
}

// ---------------------------------------------------------------------------
extern "C" void kernel_launch(void* const* d_in, const int* in_sizes, int n_in,
                              void* d_out, int out_size, void* d_ws, size_t ws_size,
                              hipStream_t stream)
{
    const float* x   = (const float*)d_in[0];
    const float* nd  = (const float*)d_in[1];
    const float* cls = (const float*)d_in[2];
    // d_in[3] (children) unused: complete 8-ary tree, child = 8i+1+j if <8192
    const float* W1 = (const float*)d_in[4];
    const float* b1 = (const float*)d_in[5];
    const float* W2 = (const float*)d_in[6];
    const float* b2 = (const float*)d_in[7];
    const float* W3 = (const float*)d_in[8];
    const float* b3 = (const float*)d_in[9];
    const float* W4 = (const float*)d_in[10];
    const float* b4 = (const float*)d_in[11];

    float* ws   = (float*)d_ws;
    float* qx   = ws;                        // [NQ][2]
    float* embf = ws + 2 * NQ;               // [MN][2]
    float* p2f  = ws + 2 * (NQ + MN);        // [NINT][2]
    float* w2t  = p2f + 2 * NINT;            // [100][100]
    float* w3p  = w2t + 100 * 100;           // [100][32] padded rows

    transpose_w2<<<52, 256, 0, stream>>>(W2, w2t, W3, w3p);

    mlp_kernel<<<(NQ + MN) / 64, 64, 0, stream>>>(
        x, nd, W1, b1, w2t, b2, w3p, b3, W4, b4, qx);

    prob2_kernel<<<NINT / 256, 256, 0, stream>>>(
        (const float2*)embf, (const float2*)cls, (float2*)p2f);

    traverse_kernel<<<NQ / 256, 256, 0, stream>>>(
        qx, (const float2*)embf, (const float2*)p2f, (float*)d_out);
}

// Round 7
// 159.874 us; speedup vs baseline: 1.8848x; 1.8848x over previous
//
#include <hip/hip_runtime.h>
#include <math.h>

#define NQ 131072
#define MN 8192
#define NINT 1024          // internal nodes: 8*i+1 < 8192 -> i <= 1023
#define DEPTHT 16
#define EPSD 1e-6f
#define BIGD 1e9f

// ---------------------------------------------------------------------------
// R16. Journal (do not retry):
//  R10 convoy barriers 77.9 | R11 w3->LDS 80.0 | R12 bank fix neutral
//  R13 half-grid: mlp PER-WAVE LATENCY bound (grid-independent 71.8)
//  R14 readlane 114 (VALU->SGPR hazards) | R15 VMEM bcast 224 (reg spill)
//  VERDICT mlp: ~70us is the floor under the bit-identity contract —
//    2176 waves (1 row/lane, fixed) = 2.1/SIMD cannot hide the SGPR-forced
//    chunked s_load drains; all 3 alternate transports measured worse.
//    mlp is FROZEN at the R0 dag/launch below.
//  R16: attack the unexplained ~84us of non-mlp time:
//    (1) traverse loses LDS staging — emb (64KB) is L1/L2-resident and the
//        8 children of cur are CONTIGUOUS (one cache line); staging was
//        possibly pure overhead (common-mistake #7).
//    (2) prob2 dispatch deleted — stop-mixture computed inline at the
//        (single) stop per query, prob2 dag replicated VERBATIM -> same bits.
//  Fork: total 95-115 => traverse was the rock. total ~150 => residual is
//  dispatch overhead -> next round: single cooperative kernel + grid.sync.
// ---------------------------------------------------------------------------

// ---------------------------------------------------------------------------
// Kernel 0: transpose W2 [k][j] -> W2T [j][k] (contiguous rows for s_load).
// ---------------------------------------------------------------------------
__global__ __launch_bounds__(256) void transpose_w2(
    const float* __restrict__ W2, float* __restrict__ W2T)
{
    const int i = blockIdx.x * 256 + threadIdx.x;
    if (i < 100 * 100) {
        const int k = i / 100, j = i - k * 100;
        W2T[j * 100 + k] = W2[i];
    }
}

// ---------------------------------------------------------------------------
// Kernel 1: MLP 2 -> 100 -> 100 -> 30 -> 2, one row per thread.
// EXACT R0 69-72us version. FROZEN — see journal above.
// Do not touch the dag: FP association is the correctness contract (R5).
// ---------------------------------------------------------------------------
__global__ __launch_bounds__(64, 2) void mlp_kernel(
    const float* __restrict__ x, const float* __restrict__ nd,
    const float* __restrict__ W1, const float* __restrict__ b1,
    const float* __restrict__ W2T, const float* __restrict__ b2,
    const float* __restrict__ W3, const float* __restrict__ b3,
    const float* __restrict__ W4, const float* __restrict__ b4,
    float* __restrict__ outv)
{
    const int r = blockIdx.x * 64 + threadIdx.x;    // 2176*64 = 139264 exact
    const float2 xi = (r < NQ) ? ((const float2*)x)[r]
                               : ((const float2*)nd)[r - NQ];

    // ---- layer 1: h1[100] (constant indices only) ----
    float h1[100];
#pragma unroll
    for (int k = 0; k < 100; ++k)
        h1[k] = fmaxf(fmaf(xi.x, W1[k], fmaf(xi.y, W1[100 + k], b1[k])), 0.0f);

    // ---- layers 2+3 fused: h2j = relu(h1 . W2T[j] + b2[j]) folded into h3
    //      immediately (h2 never materialized); weights all s_load uniform ----
    float h3[30];
#pragma unroll
    for (int jj = 0; jj < 30; ++jj) h3[jj] = b3[jj];

    const float* w2 = W2T;
    const float* w3 = W3;
    for (int j = 0; j < 100; ++j) {
        float a0 = 0.0f, a1 = 0.0f;                 // 2 chains: hide FMA latency
#pragma unroll
        for (int k = 0; k < 100; k += 2) {
            a0 = fmaf(h1[k],     w2[k],     a0);    // w2[k]: s_load scalar
            a1 = fmaf(h1[k + 1], w2[k + 1], a1);
        }
        const float h2j = fmaxf(a0 + a1 + b2[j], 0.0f);
#pragma unroll
        for (int jj = 0; jj < 30; ++jj)
            h3[jj] = fmaf(h2j, w3[jj], h3[jj]);     // w3[jj]: s_load scalar
        w2 += 100;
        w3 += 30;
    }

    // ---- layer 4: 30 -> 2 ----
    float o0 = b4[0], o1 = b4[1];
#pragma unroll
    for (int k = 0; k < 30; ++k) {
        const float h = fmaxf(h3[k], 0.0f);
        o0 = fmaf(h, W4[2 * k],     o0);
        o1 = fmaf(h, W4[2 * k + 1], o1);
    }
    ((float2*)outv)[r] = make_float2(o0, o1);
}

// ---------------------------------------------------------------------------
// Kernel 2: per-query traversal, NO LDS (emb is cache-resident; children of
// cur are contiguous = one line). prob2 dispatch deleted: its exact dag is
// inlined at the stop (each query stops at most once). Same op order as the
// standalone prob2 kernel -> bit-identical output.
// d0 carried across steps (child dist at t == d0 at t+1), verbatim.
// ---------------------------------------------------------------------------
__global__ __launch_bounds__(256) void traverse_kernel(
    const float* __restrict__ qx, const float2* __restrict__ emb,
    const float2* __restrict__ cls, float* __restrict__ out)
{
    const int qi = blockIdx.x * 256 + threadIdx.x;  // grid = NQ/256
    const float2 qv = ((const float2*)qx)[qi];

    int cur = 0;
    float d0;
    {
        const float2 e0 = emb[0];
        const float dx = e0.x - qv.x + EPSD;
        const float dy = e0.y - qv.y + EPSD;
        d0 = sqrtf(dx * dx + dy * dy);
    }
    float prob = 0.0f, out0 = 0.0f, out1 = 0.0f;
    bool done = false;

    for (int t = 0; t < DEPTHT; ++t) {
        if (__all(done)) break;
        if (!done) {
            const int base = 8 * cur + 1;

            float dc[8];
#pragma unroll
            for (int j = 0; j < 8; ++j) {
                const int c = base + j;
                const bool v = c < MN;
                const float2 e = emb[v ? c : 0];
                const float dx = e.x - qv.x + EPSD;
                const float dy = e.y - qv.y + EPSD;
                dc[j] = v ? sqrtf(dx * dx + dy * dy) : BIGD;
            }

            // argmax(log_softmax(-d)) == first argmin(d)
            float dmin = d0;
            int amax = 0;
#pragma unroll
            for (int j = 0; j < 8; ++j)
                if (dc[j] < dmin) { dmin = dc[j]; amax = j + 1; }

            float s = expf(dmin - d0);
#pragma unroll
            for (int j = 0; j < 8; ++j) s += expf(dmin - dc[j]);
            const float max_prob = -logf(s);
            // quirk: t==0 adds max_prob twice
            const float prob_new = prob + max_prob + ((t == 0) ? max_prob : 0.0f);

            if (amax == 0) {
                if (base < MN) {
                    // ---- inline prob2 for node cur (verbatim dag) ----
                    const float2 ei = emb[cur];
                    float d2[8];
                    float m2 = BIGD;
#pragma unroll
                    for (int j = 0; j < 8; ++j) {
                        const int c = base + j;
                        const bool v = c < MN;
                        const float2 ec = emb[v ? c : 0];
                        const float dx = ei.x - ec.x + EPSD;
                        const float dy = ei.y - ec.y + EPSD;
                        d2[j] = v ? sqrtf(dx * dx + dy * dy) : BIGD;
                        m2 = fminf(m2, d2[j]);
                    }
                    float s2 = 0.0f, mix0 = 0.0f, mix1 = 0.0f;
#pragma unroll
                    for (int j = 0; j < 8; ++j) {
                        const float w = expf(m2 - d2[j]);   // exactly 0 for pads
                        s2 += w;
                        const int c = base + j;
                        if (c < MN) {
                            const float2 cv = cls[c];
                            mix0 = fmaf(w, cv.x, mix0);
                            mix1 = fmaf(w, cv.y, mix1);
                        }
                    }
                    mix0 /= s2;
                    mix1 /= s2;
                    out0 = prob_new + logf(fmaxf(mix0, 1e-30f));
                    out1 = prob_new + logf(fmaxf(mix1, 1e-30f));
                } else {                          // leaf
                    out0 = prob_new;
                    out1 = prob_new;
                }
                done = true;
            } else {
                cur  = base + amax - 1;
                d0   = dmin;                      // child dist == next d0
                prob = prob_new;
            }
        }
    }

    ((float2*)out)[qi] = make_float2(out0, out1);
}

// ---------------------------------------------------------------------------
extern "C" void kernel_launch(void* const* d_in, const int* in_sizes, int n_in,
                              void* d_out, int out_size, void* d_ws, size_t ws_size,
                              hipStream_t stream)
{
    const float* x   = (const float*)d_in[0];
    const float* nd  = (const float*)d_in[1];
    const float* cls = (const float*)d_in[2];
    // d_in[3] (children) unused: complete 8-ary tree, child = 8i+1+j if <8192
    const float* W1 = (const float*)d_in[4];
    const float* b1 = (const float*)d_in[5];
    const float* W2 = (const float*)d_in[6];
    const float* b2 = (const float*)d_in[7];
    const float* W3 = (const float*)d_in[8];
    const float* b3 = (const float*)d_in[9];
    const float* W4 = (const float*)d_in[10];
    const float* b4 = (const float*)d_in[11];

    float* ws   = (float*)d_ws;
    float* qx   = ws;                        // [NQ][2]
    float* embf = ws + 2 * NQ;               // [MN][2]  (contiguous after qx)
    float* w2t  = ws + 2 * (NQ + MN);        // [100][100]

    transpose_w2<<<40, 256, 0, stream>>>(W2, w2t);

    mlp_kernel<<<(NQ + MN) / 64, 64, 0, stream>>>(
        x, nd, W1, b1, w2t, b2, W3, b3, W4, b4, qx);

    traverse_kernel<<<NQ / 256, 256, 0, stream>>>(
        qx, (const float2*)embf, (const float2*)cls, (float*)d_out);
}